// Round 4
// baseline (398.568 us; speedup 1.0000x reference)
//
#include <hip/hip_runtime.h>

#define T_SEQ 512
#define HID   50
#define NB    8           // batch rows per block (MFMA N=16: cols 0-7 = L0 batch, 8-15 = L1 batch)
#define BLK   448         // 7 waves; wave w owns Mtiles 2w,2w+1 for BOTH layers

typedef float v4f  __attribute__((ext_vector_type(4)));
typedef _Float16 f16;
typedef f16  f16x8 __attribute__((ext_vector_type(8)));

// R14 = R13 with WAVES HALVED (13 -> 7), 2 Mtiles (= 2 epilogue items) per
// lane.  Rationale: B0..B3 are indexed by lane only -- every wave reads the
// IDENTICAL four 1KB fragments, so the post-barrier LDS flood was 52
// ds_read_b128 (~624 cyc on the one per-CU LDS pipe) of purely redundant
// traffic.  Wave count only exists to provide epilogue lane-slots; packing
// 2 items/lane keeps 448*2=896 slots >= 800 items while halving the read
// drain (28 reads ~336 cyc) and barrier-arrival skew.  The two per-lane
// epilogues interleave (ILP-2) so trans latency is hidden by issue, not idle.
// Kept from R13: duplicate-column layout (cols 8-15 mirror 0-7 so the L1
// select is reg-to-reg), CZ accumulator.  Dropped: the add-split of L1's
// chain (4 independent MFMA chains now give enough ILP).
// LDS tiles (f16, 8 k-tiles of 32): 0,1=hA buf0 (x@k62,1@k63); 2,3=hA buf1;
// 4,5=hB buf0; 6,7=hB buf1. Superstep s: rb=(s+1)&1, wb=s&1 (hazards: R9 proof).
// MFMA 16x16x32_f16: A[m=lane&15][k=(lane>>4)*8+j]; B[k=(lane>>4)*8+j][n=lane&15];
// C reg r = C[row=(lane>>4)*4+r][col=lane&15].  M layout: m=4u+g (gate-interleaved).

__device__ __forceinline__ f16x8 ldA0(const float* __restrict__ Whh0,
                                      const float* __restrict__ Wih0,
                                      const float* __restrict__ bih0,
                                      const float* __restrict__ bhh0,
                                      int m, int kb) {
    const int u = m >> 2, g = m & 3;
    f16x8 v;
    #pragma unroll
    for (int j = 0; j < 8; ++j) {
        const int k = kb + j;
        float f = 0.f;
        if (u < HID) {
            const int rho = g * HID + u;
            if (k < HID)      f = Whh0[rho * HID + k];
            else if (k == 62) f = Wih0[rho];
            else if (k == 63) f = bih0[rho] + bhh0[rho];
        }
        v[j] = (f16)f;
    }
    return v;
}

__device__ __forceinline__ f16x8 ldA1a(const float* __restrict__ Wih1,
                                       const float* __restrict__ bih1,
                                       const float* __restrict__ bhh1,
                                       int m, int kb) {
    const int u = m >> 2, g = m & 3;
    f16x8 v;
    #pragma unroll
    for (int j = 0; j < 8; ++j) {
        const int k = kb + j;
        float f = 0.f;
        if (u < HID) {
            const int rho = g * HID + u;
            if (k < HID)      f = Wih1[rho * HID + k];
            else if (k == 63) f = bih1[rho] + bhh1[rho];
        }
        v[j] = (f16)f;
    }
    return v;
}

__device__ __forceinline__ f16x8 ldA1b(const float* __restrict__ Whh1,
                                       int m, int kb) {
    const int u = m >> 2, g = m & 3;
    f16x8 v;
    #pragma unroll
    for (int j = 0; j < 8; ++j) {
        const int k = kb + j;
        float f = 0.f;
        if (u < HID && k < HID) f = Whh1[(g * HID + u) * HID + k];
        v[j] = (f16)f;
    }
    return v;
}

#define MFMA16(A, B, C) __builtin_amdgcn_mfma_f32_16x16x32_f16((A), (B), (C), 0, 0, 0)

__global__ __launch_bounds__(BLK, 1)
void lstm2_mfma(const float* __restrict__ x,
                const float* __restrict__ Wih0,
                const float* __restrict__ Whh0,
                const float* __restrict__ bih0,
                const float* __restrict__ bhh0,
                const float* __restrict__ Wih1,
                const float* __restrict__ Whh1,
                const float* __restrict__ bih1,
                const float* __restrict__ bhh1,
                const float* __restrict__ Wfc,
                const float* __restrict__ bfc,
                float* __restrict__ out)
{
    __shared__ __align__(16) f16 BPH [8 * 64 * 8];   // 8,192 B: B frags (dbuf hA/hB, dup cols)
    __shared__ f16   xs16[NB][T_SEQ];                // 8,192 B: staged x (f16)
    __shared__ float hfin[HID][NB];                  // 1,600 B: final hB fp32

    const int tid  = threadIdx.x;
    const int w    = tid >> 6;                       // 0..6: Mtile pair index
    const int lane = tid & 63;
    const int n16  = lane & 15;
    const int quad = lane >> 4;
    const int bb0  = blockIdx.x * NB;

    const float* xg = x + (long)bb0 * T_SEQ;

    // ---- one-time: zero B frags; stage x -> f16 LDS ----
    for (int i = tid; i < 8 * 64 * 8; i += BLK) BPH[i] = (f16)0.f;
    for (int i = tid; i < NB * T_SEQ; i += BLK) {
        const int n = i >> 9, tt = i & (T_SEQ - 1);
        xs16[n][tt] = (f16)xg[n * T_SEQ + tt];
    }

    // ---- one-time: weights for Mtiles 2w (item0) and 2w+1 (item1), both layers ----
    const int m0  = (2 * w)     * 16 + n16;
    const int m1  = (2 * w + 1) * 16 + n16;          // w=6: rows >= 208 -> loaders zero
    const int kb0 = quad * 8, kb1 = 32 + quad * 8;
    const f16x8 a0  = ldA0(Whh0, Wih0, bih0, bhh0, m0, kb0);  // L0 item0
    const f16x8 a1  = ldA0(Whh0, Wih0, bih0, bhh0, m0, kb1);
    const f16x8 a0p = ldA0(Whh0, Wih0, bih0, bhh0, m1, kb0);  // L0 item1
    const f16x8 a1p = ldA0(Whh0, Wih0, bih0, bhh0, m1, kb1);
    const f16x8 v0  = ldA1a(Wih1, bih1, bhh1, m0, kb0);       // L1 item0 hA-side
    const f16x8 v1  = ldA1a(Wih1, bih1, bhh1, m0, kb1);
    const f16x8 v2  = ldA1b(Whh1, m0, kb0);                   // L1 item0 hB-side
    const f16x8 v3  = ldA1b(Whh1, m0, kb1);
    const f16x8 v0p = ldA1a(Wih1, bih1, bhh1, m1, kb0);       // L1 item1 hA-side
    const f16x8 v1p = ldA1a(Wih1, bih1, bhh1, m1, kb1);
    const f16x8 v2p = ldA1b(Whh1, m1, kb0);                   // L1 item1 hB-side
    const f16x8 v3p = ldA1b(Whh1, m1, kb1);

    __syncthreads();
    // "1.0" bias (k=63) in both hA bufs, BOTH column halves; x(0) likewise
    if (tid < NB) {
        BPH[(1 * 64 + 48 + tid) * 8 + 7] = (f16)1.f;
        BPH[(1 * 64 + 56 + tid) * 8 + 7] = (f16)1.f;
        BPH[(3 * 64 + 48 + tid) * 8 + 7] = (f16)1.f;
        BPH[(3 * 64 + 56 + tid) * 8 + 7] = (f16)1.f;
        BPH[(3 * 64 + 48 + tid) * 8 + 6] = xs16[tid][0];
        BPH[(3 * 64 + 56 + tid) * 8 + 6] = xs16[tid][0];
    }
    __syncthreads();

    // per-lane: item k tracks cell (u_k, col): cols 0-7 = L0 batch n16,
    // cols 8-15 = L1 batch n16-8.  u_0 = 8w+quad, u_1 = 8w+4+quad.
    const int  u_0    = 8 * w + quad;
    const int  u_1    = 8 * w + 4 + quad;
    const bool isl0   = (n16 < 8);
    const bool valid0 = (u_0 < HID);
    const bool valid1 = (u_1 < HID);
    const int  wb0i   = (((u_0 & 31) >> 3) * 16 + (n16 & 7)) * 8 + (u_0 & 7) + (u_0 >> 5) * 512;
    const int  wb1i   = (((u_1 & 31) >> 3) * 16 + (n16 & 7)) * 8 + (u_1 & 7) + (u_1 >> 5) * 512;
    float cs0 = 0.f, cs1 = 0.f;
    const f16x8* BPF = (const f16x8*)BPH;
    const v4f CZ = {0.f, 0.f, 0.f, 0.f};            // loop-invariant zero accumulator

    #pragma clang loop unroll(disable)
    for (int s = 0; s <= T_SEQ; ++s) {
        const int rb = (s + 1) & 1, wb = s & 1;

        // shared frags: ALL waves read these same four 1KB tiles
        const f16x8 B0 = BPF[(2 * rb + 0) * 64 + lane];       // hA(s-1) k 0-31
        const f16x8 B1 = BPF[(2 * rb + 1) * 64 + lane];       // hA(s-1) k 32-63
        const f16x8 B2 = BPF[(4 + 2 * wb + 0) * 64 + lane];   // hB(s-2) k 0-31
        const f16x8 B3 = BPF[(4 + 2 * wb + 1) * 64 + lane];   // hB(s-2) k 32-63

        // 12 MFMA in 4 independent chains (depth 2,2,4,4)
        v4f D0 = MFMA16(a0,  B0, CZ);  D0 = MFMA16(a1,  B1, D0);   // L0 item0
        v4f D1 = MFMA16(a0p, B0, CZ);  D1 = MFMA16(a1p, B1, D1);   // L0 item1
        v4f E0 = MFMA16(v0,  B0, CZ);  E0 = MFMA16(v1,  B1, E0);   // L1 item0
        E0 = MFMA16(v2,  B2, E0);      E0 = MFMA16(v3,  B3, E0);
        v4f E1 = MFMA16(v0p, B0, CZ);  E1 = MFMA16(v1p, B1, E1);   // L1 item1
        E1 = MFMA16(v2p, B2, E1);      E1 = MFMA16(v3p, B3, E1);

        // select per item: cols 0-7 <- L0 (D), cols 8-15 <- L1 (E). reg-to-reg.
        v4f CA, CB;
        CA.x = isl0 ? D0.x : E0.x;  CA.y = isl0 ? D0.y : E0.y;
        CA.z = isl0 ? D0.z : E0.z;  CA.w = isl0 ? D0.w : E0.w;
        CB.x = isl0 ? D1.x : E1.x;  CB.y = isl0 ? D1.y : E1.y;
        CB.z = isl0 ? D1.z : E1.z;  CB.w = isl0 ? D1.w : E1.w;

        const bool active = isl0 ? (s < T_SEQ) : (s >= 1);

        // ---- two interleaved packed LSTM epilogues (Montgomery batched rcp) ----
        const float e1a = __expf(-CA.x),        e1b = __expf(-CB.x);
        const float e2a = __expf(-CA.y),        e2b = __expf(-CB.y);
        const float e3a = __expf(-2.f * CA.z),  e3b = __expf(-2.f * CB.z);
        const float e4a = __expf(-CA.w),        e4b = __expf(-CB.w);
        const float d1a = 1.f + e1a, d2a = 1.f + e2a, d3a = 1.f + e3a, d4a = 1.f + e4a;
        const float d1b = 1.f + e1b, d2b = 1.f + e2b, d3b = 1.f + e3b, d4b = 1.f + e4b;
        const float p2a = d1a * d2a, p3a = p2a * d3a, p4a = p3a * d4a;
        const float p2b = d1b * d2b, p3b = p2b * d3b, p4b = p3b * d4b;
        const float i4a = __builtin_amdgcn_rcpf(p4a);
        const float i4b = __builtin_amdgcn_rcpf(p4b);
        const float goa = i4a * p3a,            gob = i4b * p3b;
        const float i3a = i4a * d4a,            i3b = i4b * d4b;
        const float r3a = i3a * p2a,            r3b = i3b * p2b;
        const float i2a = i3a * d3a,            i2b = i3b * d3b;
        const float gfa = i2a * d1a,            gfb = i2b * d1b;
        const float gia = i2a * d2a,            gib = i2b * d2b;
        const float gga = fmaf(2.f, r3a, -1.f), ggb = fmaf(2.f, r3b, -1.f);
        const float ca  = fmaf(gfa, cs0, gia * gga);
        const float cbv = fmaf(gfb, cs1, gib * ggb);
        cs0 = active ? ca  : cs0;
        cs1 = active ? cbv : cs1;
        const float tha = fmaf(2.f, __builtin_amdgcn_rcpf(1.f + __expf(-2.f * cs0)), -1.f);
        const float thb = fmaf(2.f, __builtin_amdgcn_rcpf(1.f + __expf(-2.f * cs1)), -1.f);
        const float hha = goa * tha;
        const float hhb = gob * thb;

        if (active) {
            const int tb = isl0 ? (2 * wb) : (4 + 2 * rb);
            if (valid0) {
                f16* p = &BPH[tb * 512 + wb0i];
                p[0]  = (f16)hha;
                p[64] = (f16)hha;             // duplicate column half
                if (!isl0 && s == T_SEQ) hfin[u_0][n16 & 7] = hha;
            }
            if (valid1) {
                f16* p = &BPH[tb * 512 + wb1i];
                p[0]  = (f16)hhb;
                p[64] = (f16)hhb;
                if (!isl0 && s == T_SEQ) hfin[u_1][n16 & 7] = hhb;
            }
        }

        // x(s+1) -> hA write-buf @k62, both column halves; read at s+1
        if (w == 0 && lane < NB && s + 1 < T_SEQ) {
            const f16 xv = xs16[lane][s + 1];
            BPH[((2 * wb + 1) * 64 + 48 + lane) * 8 + 6] = xv;
            BPH[((2 * wb + 1) * 64 + 56 + lane) * 8 + 6] = xv;
        }

        __syncthreads();   // the ONE barrier: publishes hA(s), hB(s-1), x(s+1)
    }

    // ---- classifier: out[n][c] = hB[n] . Wfc[c] + bfc[c] ----
    if (tid < NB * 2) {
        const int nn = tid >> 1, c = tid & 1;
        float acc = bfc[c];
        #pragma unroll
        for (int u = 0; u < HID; ++u)
            acc = fmaf(Wfc[c * HID + u], hfin[u][nn], acc);
        out[(bb0 + nn) * 2 + c] = acc;
    }
}

extern "C" void kernel_launch(void* const* d_in, const int* in_sizes, int n_in,
                              void* d_out, int out_size, void* d_ws, size_t ws_size,
                              hipStream_t stream) {
    const float* x    = (const float*)d_in[0];
    const float* Wih0 = (const float*)d_in[1];
    const float* Whh0 = (const float*)d_in[2];
    const float* bih0 = (const float*)d_in[3];
    const float* bhh0 = (const float*)d_in[4];
    const float* Wih1 = (const float*)d_in[5];
    const float* Whh1 = (const float*)d_in[6];
    const float* bih1 = (const float*)d_in[7];
    const float* bhh1 = (const float*)d_in[8];
    const float* Wfc  = (const float*)d_in[9];
    const float* bfc  = (const float*)d_in[10];
    float* out = (float*)d_out;

    const int B = in_sizes[0] / T_SEQ;   // D == 1
    const int grid = B / NB;             // 2048/8 = 256 blocks -> 1 block/CU

    hipLaunchKernelGGL(lstm2_mfma, dim3(grid), dim3(BLK), 0, stream,
                       x, Wih0, Whh0, bih0, bhh0, Wih1, Whh1, bih1, bhh1,
                       Wfc, bfc, out);
}

// Round 5
// 327.308 us; speedup vs baseline: 1.2177x; 1.2177x over previous
//
#include <hip/hip_runtime.h>

#define T_SEQ 512
#define HID   50
#define NB    8           // batch rows per block (MFMA N=16: cols 0-7 = L0 batch, 8-15 = L1 batch)
#define BLK   832         // 13 waves; wave w owns L0 Mtile w AND L1 Mtile w

typedef float v4f  __attribute__((ext_vector_type(4)));
typedef _Float16 f16;
typedef f16  f16x8 __attribute__((ext_vector_type(8)));

// R15 = R13 (best verified: 344us; R14's wave-halving regressed -> keep 13
// waves) + UNROLL x2 + BOUNDARY PEEL, attacking the VALU-issue budget
// (~270 cyc/wave/step, 55% VALUBusy):
//  (1) manual 2-step unroll makes rb/wb compile-time: the 4 ds_read_b128
//      become immediate offsets off one lane*16 base; L0/L1 h-writes become
//      two loop-invariant pointers (pwOdd/pwEven) + immediate offsets.
//      Per-step address arithmetic ~0.
//  (2) peel s=0 (L0-only) and s=512 (L1-only): the 511-step body drops the
//      `active` cndmasks and the isl0?tb write-select entirely.
//  (3) keep: dup-column layout (reg-to-reg CC select), CZ accumulator,
//      Montgomery 7-transcendental epilogue, one barrier/step.
// LDS tiles (f16, 8 k-tiles of 32): 0,1=hA buf0 (x@k62,1@k63); 2,3=hA buf1;
// 4,5=hB buf0; 6,7=hB buf1.  Step s: reads hA tiles 2rb..+1, hB 4+2wb..+1;
// L0 writes tile 2wb, L1 writes 4+2rb (rb=(s+1)&1, wb=s&1; hazards: R9 proof).
// ODD s (rb=0,wb=1): read 0,1,6,7; L0->tile2, L1->tile4; x-feed tile3.
// EVEN s (rb=1,wb=0): read 2,3,4,5; L0->tile0, L1->tile6; x-feed tile1.
// MFMA 16x16x32_f16: A[m=lane&15][k=(lane>>4)*8+j]; B[k=(lane>>4)*8+j][n=lane&15];
// C reg r = C[row=(lane>>4)*4+r][col=lane&15].  M layout: m=4u+g (gate-interleaved).

__device__ __forceinline__ f16x8 ldA0(const float* __restrict__ Whh0,
                                      const float* __restrict__ Wih0,
                                      const float* __restrict__ bih0,
                                      const float* __restrict__ bhh0,
                                      int m, int kb) {
    const int u = m >> 2, g = m & 3;
    f16x8 v;
    #pragma unroll
    for (int j = 0; j < 8; ++j) {
        const int k = kb + j;
        float f = 0.f;
        if (u < HID) {
            const int rho = g * HID + u;
            if (k < HID)      f = Whh0[rho * HID + k];
            else if (k == 62) f = Wih0[rho];
            else if (k == 63) f = bih0[rho] + bhh0[rho];
        }
        v[j] = (f16)f;
    }
    return v;
}

__device__ __forceinline__ f16x8 ldA1a(const float* __restrict__ Wih1,
                                       const float* __restrict__ bih1,
                                       const float* __restrict__ bhh1,
                                       int m, int kb) {
    const int u = m >> 2, g = m & 3;
    f16x8 v;
    #pragma unroll
    for (int j = 0; j < 8; ++j) {
        const int k = kb + j;
        float f = 0.f;
        if (u < HID) {
            const int rho = g * HID + u;
            if (k < HID)      f = Wih1[rho * HID + k];
            else if (k == 63) f = bih1[rho] + bhh1[rho];
        }
        v[j] = (f16)f;
    }
    return v;
}

__device__ __forceinline__ f16x8 ldA1b(const float* __restrict__ Whh1,
                                       int m, int kb) {
    const int u = m >> 2, g = m & 3;
    f16x8 v;
    #pragma unroll
    for (int j = 0; j < 8; ++j) {
        const int k = kb + j;
        float f = 0.f;
        if (u < HID && k < HID) f = Whh1[(g * HID + u) * HID + k];
        v[j] = (f16)f;
    }
    return v;
}

#define MFMA16(A, B, C) __builtin_amdgcn_mfma_f32_16x16x32_f16((A), (B), (C), 0, 0, 0)

// packed LSTM epilogue, Montgomery batched rcp (7 transcendentals).
// Updates cs unconditionally; returns h.
__device__ __forceinline__ float lstm_epi(const v4f CC, float& cs) {
    const float e1 = __expf(-CC.x);
    const float e2 = __expf(-CC.y);
    const float e3 = __expf(-2.f * CC.z);
    const float e4 = __expf(-CC.w);
    const float d1 = 1.f + e1, d2 = 1.f + e2, d3 = 1.f + e3, d4 = 1.f + e4;
    const float p2 = d1 * d2, p3 = p2 * d3, p4 = p3 * d4;
    const float i4 = __builtin_amdgcn_rcpf(p4);
    const float go = i4 * p3;                 /* 1/d4 */
    const float i3 = i4 * d4;
    const float r3 = i3 * p2;                 /* 1/d3 */
    const float i2 = i3 * d3;
    const float gf = i2 * d1;                 /* 1/d2 */
    const float gi = i2 * d2;                 /* 1/d1 */
    const float gg = fmaf(2.f, r3, -1.f);
    cs = fmaf(gf, cs, gi * gg);
    const float th = fmaf(2.f, __builtin_amdgcn_rcpf(1.f + __expf(-2.f * cs)), -1.f);
    return go * th;
}

__global__ __launch_bounds__(BLK, 1)
void lstm2_mfma(const float* __restrict__ x,
                const float* __restrict__ Wih0,
                const float* __restrict__ Whh0,
                const float* __restrict__ bih0,
                const float* __restrict__ bhh0,
                const float* __restrict__ Wih1,
                const float* __restrict__ Whh1,
                const float* __restrict__ bih1,
                const float* __restrict__ bhh1,
                const float* __restrict__ Wfc,
                const float* __restrict__ bfc,
                float* __restrict__ out)
{
    __shared__ __align__(16) f16 BPH [8 * 64 * 8];   // 8,192 B: B frags (dbuf hA/hB, dup cols)
    __shared__ f16   xs16[NB][T_SEQ];                // 8,192 B: staged x (f16)
    __shared__ float hfin[HID][NB];                  // 1,600 B: final hB fp32

    const int tid  = threadIdx.x;
    const int w    = tid >> 6;                       // 0..12 = Mtile index (both layers)
    const int lane = tid & 63;
    const int n16  = lane & 15;
    const int quad = lane >> 4;
    const int bb0  = blockIdx.x * NB;

    const float* xg = x + (long)bb0 * T_SEQ;

    // ---- one-time: zero B frags; stage x -> f16 LDS ----
    for (int i = tid; i < 8 * 64 * 8; i += BLK) BPH[i] = (f16)0.f;
    for (int i = tid; i < NB * T_SEQ; i += BLK) {
        const int n = i >> 9, tt = i & (T_SEQ - 1);
        xs16[n][tt] = (f16)xg[n * T_SEQ + tt];
    }

    // ---- one-time: this wave's weights for BOTH layers, Mtile w ----
    const int m   = w * 16 + n16;
    const int kb0 = quad * 8, kb1 = 32 + quad * 8;
    const f16x8 a0 = ldA0(Whh0, Wih0, bih0, bhh0, m, kb0);   // L0: [Whh0|x|b]
    const f16x8 a1 = ldA0(Whh0, Wih0, bih0, bhh0, m, kb1);
    const f16x8 v0 = ldA1a(Wih1, bih1, bhh1, m, kb0);        // L1: hA-side [Wih1|b]
    const f16x8 v1 = ldA1a(Wih1, bih1, bhh1, m, kb1);
    const f16x8 v2 = ldA1b(Whh1, m, kb0);                    // L1: hB-side Whh1
    const f16x8 v3 = ldA1b(Whh1, m, kb1);

    __syncthreads();
    // "1.0" bias (k=63) in both hA bufs, BOTH column halves; x(0) likewise
    if (tid < NB) {
        BPH[(1 * 64 + 48 + tid) * 8 + 7] = (f16)1.f;
        BPH[(1 * 64 + 56 + tid) * 8 + 7] = (f16)1.f;
        BPH[(3 * 64 + 48 + tid) * 8 + 7] = (f16)1.f;
        BPH[(3 * 64 + 56 + tid) * 8 + 7] = (f16)1.f;
        BPH[(3 * 64 + 48 + tid) * 8 + 6] = xs16[tid][0];
        BPH[(3 * 64 + 56 + tid) * 8 + 6] = xs16[tid][0];
    }
    __syncthreads();

    // per-lane cell state: cols 0-7 track L0 cell (u_, n16), cols 8-15 track
    // L1 cell (u_, n16-8).  u_ fixed per lane for all steps.
    const int  u_    = w * 4 + quad;
    const bool isl0  = (n16 < 8);
    const bool valid = (u_ < HID);
    // step-invariant write pointers (dup-column: [0] and [64] elems = +0/+128B)
    const int  wbase = (((u_ & 31) >> 3) * 16 + (n16 & 7)) * 8 + (u_ & 7) + (u_ >> 5) * 512;
    f16* const pwOdd  = &BPH[wbase + (isl0 ? 2 : 4) * 512];  // ODD s : L0 tile2, L1 tile4
    f16* const pwEven = &BPH[wbase + (isl0 ? 0 : 6) * 512];  // EVEN s: L0 tile0, L1 tile6
    float cs = 0.f;
    const f16x8* BPF = (const f16x8*)BPH;
    const v4f CZ = {0.f, 0.f, 0.f, 0.f};            // loop-invariant zero accumulator

    // ---- peeled s = 0: L0 only (reads tiles 2,3; writes tile0; x-feed tile1) ----
    {
        const f16x8 B0 = BPF[2 * 64 + lane];
        const f16x8 B1 = BPF[3 * 64 + lane];
        v4f D = MFMA16(a0, B0, CZ);  D = MFMA16(a1, B1, D);
        const float cs_sav = cs;
        const float hh = lstm_epi(D, cs);
        if (!isl0) cs = cs_sav;                      // L1 lanes: no update at s=0
        if (valid && isl0) { const f16 hv = (f16)hh; pwEven[0] = hv; pwEven[64] = hv; }
        if (w == 0 && lane < NB) {
            const f16 xv = xs16[lane][1];
            BPH[(1 * 64 + 48 + lane) * 8 + 6] = xv;
            BPH[(1 * 64 + 56 + lane) * 8 + 6] = xv;
        }
        __syncthreads();
    }

    // body step: both layers active, compile-time tiles/pointers.
#define STEP(TA, TB, PW, XT, XS, DOX) {                                       \
        const f16x8 B0 = BPF[(TA)     * 64 + lane];                           \
        const f16x8 B1 = BPF[(TA + 1) * 64 + lane];                           \
        const f16x8 B2 = BPF[(TB)     * 64 + lane];                           \
        const f16x8 B3 = BPF[(TB + 1) * 64 + lane];                           \
        v4f D = MFMA16(a0, B0, CZ);  D = MFMA16(a1, B1, D);                   \
        v4f E = MFMA16(v0, B0, CZ);  E = MFMA16(v1, B1, E);                   \
        E = MFMA16(v2, B2, E);       E = MFMA16(v3, B3, E);                   \
        v4f CC;                                                               \
        CC.x = isl0 ? D.x : E.x;  CC.y = isl0 ? D.y : E.y;                    \
        CC.z = isl0 ? D.z : E.z;  CC.w = isl0 ? D.w : E.w;                    \
        const float hh = lstm_epi(CC, cs);                                    \
        if (valid) { const f16 hv = (f16)hh; (PW)[0] = hv; (PW)[64] = hv; }   \
        if ((DOX) && w == 0 && lane < NB) {                                   \
            const f16 xv = xs16[lane][(XS)];                                  \
            BPH[((XT) * 64 + 48 + lane) * 8 + 6] = xv;                        \
            BPH[((XT) * 64 + 56 + lane) * 8 + 6] = xv;                        \
        }                                                                     \
        __syncthreads(); }

    // ---- main: s = 1..510 in ODD/EVEN pairs, then s = 511 (no x-feed) ----
    #pragma clang loop unroll(disable)
    for (int s = 1; s < 511; s += 2) {
        STEP(0, 6, pwOdd,  3, s + 1, true)    // ODD s : read 0,1,6,7
        STEP(2, 4, pwEven, 1, s + 2, true)    // EVEN s: read 2,3,4,5
    }
    STEP(0, 6, pwOdd, 3, 0, false)            // s = 511

    // ---- peeled s = 512: L1 finish only (reads tiles 2,3,4,5) ----
    {
        const f16x8 B0 = BPF[2 * 64 + lane];
        const f16x8 B1 = BPF[3 * 64 + lane];
        const f16x8 B2 = BPF[4 * 64 + lane];
        const f16x8 B3 = BPF[5 * 64 + lane];
        v4f E = MFMA16(v0, B0, CZ);  E = MFMA16(v1, B1, E);
        E = MFMA16(v2, B2, E);       E = MFMA16(v3, B3, E);
        const float hh = lstm_epi(E, cs);
        if (!isl0 && valid) hfin[u_][n16 & 7] = hh;
        __syncthreads();
    }

    // ---- classifier: out[n][c] = hB[n] . Wfc[c] + bfc[c] ----
    if (tid < NB * 2) {
        const int nn = tid >> 1, c = tid & 1;
        float acc = bfc[c];
        #pragma unroll
        for (int u = 0; u < HID; ++u)
            acc = fmaf(Wfc[c * HID + u], hfin[u][nn], acc);
        out[(bb0 + nn) * 2 + c] = acc;
    }
}

extern "C" void kernel_launch(void* const* d_in, const int* in_sizes, int n_in,
                              void* d_out, int out_size, void* d_ws, size_t ws_size,
                              hipStream_t stream) {
    const float* x    = (const float*)d_in[0];
    const float* Wih0 = (const float*)d_in[1];
    const float* Whh0 = (const float*)d_in[2];
    const float* bih0 = (const float*)d_in[3];
    const float* bhh0 = (const float*)d_in[4];
    const float* Wih1 = (const float*)d_in[5];
    const float* Whh1 = (const float*)d_in[6];
    const float* bih1 = (const float*)d_in[7];
    const float* bhh1 = (const float*)d_in[8];
    const float* Wfc  = (const float*)d_in[9];
    const float* bfc  = (const float*)d_in[10];
    float* out = (float*)d_out;

    const int B = in_sizes[0] / T_SEQ;   // D == 1
    const int grid = B / NB;             // 2048/8 = 256 blocks -> 1 block/CU

    hipLaunchKernelGGL(lstm2_mfma, dim3(grid), dim3(BLK), 0, stream,
                       x, Wih0, Whh0, bih0, bhh0, Wih1, Whh1, bih1, bhh1,
                       Wfc, bfc, out);
}